// Round 3
// baseline (1274.620 us; speedup 1.0000x reference)
//
#include <hip/hip_runtime.h>
#include <hip/hip_bf16.h>
#include <math.h>

// Problem: b=4, n=4096, d=64.
// d_out (fp32 concat): [loss(1)] [pred_attn 4*4096*4096] [true_attn 4*4096*4096]
//
// ws (ushort elements): qbh 0, qbl 1048576, kbh 2097152, kbl 3145728 (4*4096*64 each)
//   qfh 4194304, qfl 6291456, kfh 8388608, kfl 10485760 (4*4096*128 each)
//   then float partials[16384] at ushort offset 12582912.

#define B 4
#define N 4096
#define D 64
#define NROWS (B * N)
#define ATTN_ELEMS ((size_t)B * N * N)

typedef __attribute__((ext_vector_type(8))) short short8;   // 8 bf16 = 4 VGPRs
typedef __attribute__((ext_vector_type(4))) float float4v;  // MFMA C/D
typedef unsigned short ushort_t;

#define FAST_EXP(x) __builtin_amdgcn_exp2f((x) * 1.44269504f)
#define FAST_LOG(x) (__builtin_amdgcn_logf(x) * 0.69314718f)

__device__ __forceinline__ void split_bf16(float x, ushort_t& hi, ushort_t& lo) {
  __hip_bfloat16 h = __float2bfloat16(x);
  float r = x - __bfloat162float(h);
  __hip_bfloat16 l = __float2bfloat16(r);
  hi = *(ushort_t*)&h;
  lo = *(ushort_t*)&l;
}

__device__ __forceinline__ void gld16(const void* g, void* l) {
  __builtin_amdgcn_global_load_lds(
      (const __attribute__((address_space(1))) unsigned int*)g,
      (__attribute__((address_space(3))) unsigned int*)l, 16, 0, 0);
}

// ---------------------------------------------------------------------------
// Kernel 1: projections + feature maps + split-bf16.
// 256 blocks x 256 thr; 64 rows/block (16 rows/wave). Hidden tile staged to
// LDS coalesced; W rows live in registers (one transposed L2 read per thread,
// reused across 16 rows). Inner loop: LDS-broadcast float4 x W-register FMAs.
// ---------------------------------------------------------------------------
__global__ __launch_bounds__(256) void proj_kernel(
    const float* __restrict__ hidden,
    const float* __restrict__ Wq_mlp, const float* __restrict__ bq_mlp,
    const float* __restrict__ Wk_mlp, const float* __restrict__ bk_mlp,
    const float* __restrict__ Wq_base, const float* __restrict__ Wk_base,
    ushort_t* __restrict__ ws) {
  ushort_t* qbh = ws;
  ushort_t* qbl = ws + 1048576;
  ushort_t* kbh = ws + 2097152;
  ushort_t* kbl = ws + 3145728;
  ushort_t* qfh = ws + 4194304;
  ushort_t* qfl = ws + 6291456;
  ushort_t* kfh = ws + 8388608;
  ushort_t* kfl = ws + 10485760;

  const int tid = threadIdx.x;
  const int e = tid & 63;        // output feature
  const int w = tid >> 6;        // wave id -> row group
  const int row0 = blockIdx.x * 64;

  __shared__ float4 hs4[1024];   // 64 rows x 16 float4

  // coalesced stage of hidden tile
  const float4* g4 = (const float4*)(hidden + (size_t)row0 * D);
  for (int v = tid; v < 1024; v += 256) hs4[v] = g4[v];
  __syncthreads();

  // ---- pass Q ----
  {
    float4 wb[16], wm[16];
    const float4* pb = (const float4*)(Wq_base + e * D);
    const float4* pm = (const float4*)(Wq_mlp + e * D);
#pragma unroll
    for (int i = 0; i < 16; ++i) { wb[i] = pb[i]; wm[i] = pm[i]; }
    const float bias = bq_mlp[e];
#pragma unroll
    for (int rr = 0; rr < 16; ++rr) {
      const int r = w * 16 + rr;
      float ab = 0.f, z = bias;
#pragma unroll
      for (int d4 = 0; d4 < 16; ++d4) {
        float4 hv = hs4[r * 16 + d4];
        ab += hv.x * wb[d4].x + hv.y * wb[d4].y + hv.z * wb[d4].z + hv.w * wb[d4].w;
        z  += hv.x * wm[d4].x + hv.y * wm[d4].y + hv.z * wm[d4].z + hv.w * wm[d4].w;
      }
      const size_t row = row0 + r;
      ushort_t hi, lo;
      split_bf16(ab, hi, lo);
      qbh[row * 64 + e] = hi;  qbl[row * 64 + e] = lo;
      split_bf16(FAST_EXP(z), hi, lo);
      qfh[row * 128 + e] = hi; qfl[row * 128 + e] = lo;
      split_bf16(FAST_EXP(-z), hi, lo);
      qfh[row * 128 + 64 + e] = hi; qfl[row * 128 + 64 + e] = lo;
    }
  }

  // ---- pass K ----
  {
    float4 wb[16], wm[16];
    const float4* pb = (const float4*)(Wk_base + e * D);
    const float4* pm = (const float4*)(Wk_mlp + e * D);
#pragma unroll
    for (int i = 0; i < 16; ++i) { wb[i] = pb[i]; wm[i] = pm[i]; }
    const float bias = bk_mlp[e];
#pragma unroll
    for (int rr = 0; rr < 16; ++rr) {
      const int r = w * 16 + rr;
      float ab = 0.f, z = bias;
#pragma unroll
      for (int d4 = 0; d4 < 16; ++d4) {
        float4 hv = hs4[r * 16 + d4];
        ab += hv.x * wb[d4].x + hv.y * wb[d4].y + hv.z * wb[d4].z + hv.w * wb[d4].w;
        z  += hv.x * wm[d4].x + hv.y * wm[d4].y + hv.z * wm[d4].z + hv.w * wm[d4].w;
      }
      const size_t row = row0 + r;
      ushort_t hi, lo;
      split_bf16(ab, hi, lo);
      kbh[row * 64 + e] = hi;  kbl[row * 64 + e] = lo;
      split_bf16(FAST_EXP(z), hi, lo);
      kfh[row * 128 + e] = hi; kfl[row * 128 + e] = lo;
      split_bf16(FAST_EXP(-z), hi, lo);
      kfh[row * 128 + 64 + e] = hi; kfl[row * 128 + 64 + e] = lo;
    }
  }
}

// ---------------------------------------------------------------------------
// Kernel 2: both raw score matrices via split-bf16 MFMA (3 MFMAs per product:
// Ah*Bh + Ah*Bl + Al*Bh, fp32 accumulate). 128x128 tile / block, 4 waves,
// wave = 64x64 quadrant as 4x4 of 16x16x32 tiles. Staging via
// global_load_lds width=16 into unpadded [128 x 32] bf16 buffers (m97 layout:
// wave-uniform base + lane*16 — padding would break it).
// ---------------------------------------------------------------------------
#define BK 32

__global__ __launch_bounds__(256) void scores_kernel(
    const ushort_t* __restrict__ ws, float* __restrict__ out) {
  const ushort_t* qbh = ws;
  const ushort_t* qbl = ws + 1048576;
  const ushort_t* kbh = ws + 2097152;
  const ushort_t* kbl = ws + 3145728;
  const ushort_t* qfh = ws + 4194304;
  const ushort_t* qfl = ws + 6291456;
  const ushort_t* kfh = ws + 8388608;
  const ushort_t* kfl = ws + 10485760;

  __shared__ __align__(16) ushort_t sAh[128 * BK];
  __shared__ __align__(16) ushort_t sAl[128 * BK];
  __shared__ __align__(16) ushort_t sBh[128 * BK];
  __shared__ __align__(16) ushort_t sBl[128 * BK];

  const int bt = blockIdx.z;
  const int m0 = blockIdx.y * 128;
  const int n0 = blockIdx.x * 128;
  const int tid = threadIdx.x;
  const int lane = tid & 63;
  const int w = tid >> 6;
  const int qr = w >> 1, qc = w & 1;   // quadrant row/col
  const int fr = lane & 15;            // fragment row (m or n) within 16
  const int quad = lane >> 4;          // 0..3 -> k-slice / acc rows

  const size_t rowb = (size_t)bt * N;
  float* pred = out + 1;
  float* tru  = out + 1 + ATTN_ELEMS;

#pragma unroll
  for (int phase = 0; phase < 2; ++phase) {
    const ushort_t* Ah = phase ? qfh : qbh;
    const ushort_t* Al = phase ? qfl : qbl;
    const ushort_t* Bh = phase ? kfh : kbh;
    const ushort_t* Bl = phase ? kfl : kbl;
    const int Krow = phase ? 128 : 64;
    const int nchunk = Krow / BK;
    const float scale = phase ? 1.0f : 0.125f;
    float* dst = phase ? pred : tru;

    float4v acc[4][4];
#pragma unroll
    for (int i = 0; i < 4; ++i)
#pragma unroll
      for (int j = 0; j < 4; ++j) acc[i][j] = (float4v)0.f;

    for (int ck = 0; ck < nchunk; ++ck) {
      const int kc = ck * BK;
      __syncthreads();  // previous chunk's LDS reads done
      // stage 4 x (128x32 bf16 = 8 KB): 512 16B units each, 2/thread
      for (int u = tid; u < 512; u += 256) {
        const int r = u >> 2;
        const int c8 = (u & 3) * 8;
        const size_t goffA = (size_t)(rowb + m0 + r) * Krow + kc + c8;
        const size_t goffB = (size_t)(rowb + n0 + r) * Krow + kc + c8;
        gld16(Ah + goffA, &sAh[u * 8]);
        gld16(Al + goffA, &sAl[u * 8]);
        gld16(Bh + goffB, &sBh[u * 8]);
        gld16(Bl + goffB, &sBl[u * 8]);
      }
      __syncthreads();  // compiler drains vmcnt before barrier

      short8 ah[4], al[4], bh[4], bl[4];
#pragma unroll
      for (int t = 0; t < 4; ++t) {
        const int ra = (qr * 64 + t * 16 + fr) * BK + 8 * quad;
        const int rb = (qc * 64 + t * 16 + fr) * BK + 8 * quad;
        ah[t] = *(const short8*)&sAh[ra];
        al[t] = *(const short8*)&sAl[ra];
        bh[t] = *(const short8*)&sBh[rb];
        bl[t] = *(const short8*)&sBl[rb];
      }
#pragma unroll
      for (int tm = 0; tm < 4; ++tm)
#pragma unroll
        for (int tn = 0; tn < 4; ++tn) {
          acc[tm][tn] = __builtin_amdgcn_mfma_f32_16x16x32_bf16(
              ah[tm], bh[tn], acc[tm][tn], 0, 0, 0);
          acc[tm][tn] = __builtin_amdgcn_mfma_f32_16x16x32_bf16(
              ah[tm], bl[tn], acc[tm][tn], 0, 0, 0);
          acc[tm][tn] = __builtin_amdgcn_mfma_f32_16x16x32_bf16(
              al[tm], bh[tn], acc[tm][tn], 0, 0, 0);
        }
    }

    // C layout: within 16x16 tile, col = fr, row = quad*4 + reg
#pragma unroll
    for (int tm = 0; tm < 4; ++tm) {
      const int rbase = m0 + qr * 64 + tm * 16 + quad * 4;
#pragma unroll
      for (int tn = 0; tn < 4; ++tn) {
        const int c = n0 + qc * 64 + tn * 16 + fr;
        float4v v = acc[tm][tn];
#pragma unroll
        for (int reg = 0; reg < 4; ++reg)
          dst[(rowb + rbase + reg) * N + c] = v[reg] * scale;
      }
    }
    __syncthreads();  // acc write-out before phase 2 restages LDS
  }
}

// ---------------------------------------------------------------------------
// Kernel 3: in-place row softmax (both matrices) + per-row loss partial.
// Hardware transcendentals (v_exp_f32 / v_log_f32).
// ---------------------------------------------------------------------------
__device__ __forceinline__ float block_reduce(float v, bool is_max, float* red) {
#pragma unroll
  for (int o = 32; o > 0; o >>= 1) {
    float other = __shfl_down(v, o);
    v = is_max ? fmaxf(v, other) : (v + other);
  }
  int w = threadIdx.x >> 6;
  __syncthreads();
  if ((threadIdx.x & 63) == 0) red[w] = v;
  __syncthreads();
  return is_max ? fmaxf(fmaxf(red[0], red[1]), fmaxf(red[2], red[3]))
                : (red[0] + red[1] + red[2] + red[3]);
}

__global__ __launch_bounds__(256) void softmax_loss_kernel(
    float* __restrict__ out, float* __restrict__ partials) {
  const size_t r = blockIdx.x;
  float* pred = out + 1 + r * N;
  float* tru  = out + 1 + ATTN_ELEMS + r * N;
  const int tid = threadIdx.x;

  __shared__ float red[4];

  float lt[16], lp[16];
#pragma unroll
  for (int i = 0; i < 16; ++i) {
    lt[i] = tru[tid + 256 * i];
    lp[i] = pred[tid + 256 * i];
  }

  float mt_ = -INFINITY, mp_ = -INFINITY;
#pragma unroll
  for (int i = 0; i < 16; ++i) {
    mt_ = fmaxf(mt_, lt[i]);
    mp_ = fmaxf(mp_, lp[i]);
  }
  const float MT = block_reduce(mt_, true, red);
  const float MP = block_reduce(mp_, true, red);

  float st = 0.f, sp = 0.f;
#pragma unroll
  for (int i = 0; i < 16; ++i) {
    lt[i] = FAST_EXP(lt[i] - MT);
    st += lt[i];
    lp[i] = FAST_EXP(lp[i] - MP);
    sp += lp[i];
  }
  const float ST = block_reduce(st, false, red);
  const float SP = block_reduce(sp, false, red);
  const float it_ = 1.f / ST, ip_ = 1.f / SP;

  float lloss = 0.f;
#pragma unroll
  for (int i = 0; i < 16; ++i) {
    float t = lt[i] * it_;
    float p = lp[i] * ip_;
    tru[tid + 256 * i] = t;
    pred[tid + 256 * i] = p;
    lloss -= t * FAST_LOG(p + 1e-9f);
  }
  lloss = block_reduce(lloss, false, red);
  if (tid == 0) partials[r] = lloss;
}

// ---------------------------------------------------------------------------
// Kernel 4: reduce 16384 partials -> out[0] = mean.
// ---------------------------------------------------------------------------
__global__ __launch_bounds__(256) void reduce_loss_kernel(
    const float* __restrict__ partials, float* __restrict__ out) {
  const int tid = threadIdx.x;
  __shared__ float red[4];
  float s = 0.f;
  for (int i = tid; i < NROWS; i += 256) s += partials[i];
  s = block_reduce(s, false, red);
  if (tid == 0) out[0] = s * (1.0f / (float)NROWS);
}

// ---------------------------------------------------------------------------
extern "C" void kernel_launch(void* const* d_in, const int* in_sizes, int n_in,
                              void* d_out, int out_size, void* d_ws, size_t ws_size,
                              hipStream_t stream) {
  const float* hidden  = (const float*)d_in[0];
  const float* Wq_mlp  = (const float*)d_in[1];
  const float* bq_mlp  = (const float*)d_in[2];
  const float* Wk_mlp  = (const float*)d_in[3];
  const float* bk_mlp  = (const float*)d_in[4];
  const float* Wq_base = (const float*)d_in[5];
  const float* Wk_base = (const float*)d_in[6];
  float* out = (float*)d_out;
  ushort_t* ws = (ushort_t*)d_ws;
  float* partials = (float*)(ws + 12582912);

  proj_kernel<<<NROWS / 64, 256, 0, stream>>>(hidden, Wq_mlp, bq_mlp, Wk_mlp,
                                              bk_mlp, Wq_base, Wk_base, ws);
  scores_kernel<<<dim3(32, 32, B), 256, 0, stream>>>(ws, out);
  softmax_loss_kernel<<<NROWS, 256, 0, stream>>>(out, partials);
  reduce_loss_kernel<<<1, 256, 0, stream>>>(partials, out);
}